// Round 6
// baseline (1717.305 us; speedup 1.0000x reference)
//
#include <hip/hip_runtime.h>
#include <math.h>

#define BB 16
#define CH 64
#define SS 128
#define HH 137
#define XS 140            // padded x-stride (16B-aligned float4)
#define CS (137 * 140)    // per-channel stride = 19180
#define MM 16
#define KK 32
#define NL 4
#define NROW 140288       // BB*CH*HH rows of (bo,x)

__device__ __forceinline__ float gelu_f(float x) {
    return 0.5f * x * (1.0f + erff(x * 0.70710678118654752440f));
}

// ---- init: twiddles + fused tail weights + WTy (32x144 inv-y GEMM weights) ----
__global__ void k_init(float2* __restrict__ Wy, float2* __restrict__ Wx,
                       float2* __restrict__ WyT, float* __restrict__ wcomb,
                       float* __restrict__ WTy,
                       const float* __restrict__ m2w, const float* __restrict__ wwp) {
    int t = blockIdx.x * 256 + threadIdx.x;
    const double PI2 = 6.283185307179586476925286766559;
    if (t < 2192) {                       // Wy[y*16+ky]
        int y = t >> 4, k = t & 15;
        int m = (y * k) % HH;
        double ang = -PI2 * (double)m / (double)HH;
        Wy[t] = make_float2((float)cos(ang), (float)sin(ang));
    } else if (t < 6576) {                // Wx[x*32+ki]
        int u = t - 2192;
        int x = u >> 5, ki = u & 31;
        int K = (ki < 16) ? ki : (105 + ki);
        int m = (x * K) % HH;
        double ang = -PI2 * (double)m / (double)HH;
        Wx[u] = make_float2((float)cos(ang), (float)sin(ang));
    } else if (t < 8768) {                // WyT[ky*137+y]
        int u = t - 6576;
        int ky = u / 137, y = u - ky * 137;
        int m = (y * ky) % HH;
        double ang = -PI2 * (double)m / (double)HH;
        WyT[u] = make_float2((float)cos(ang), (float)sin(ang));
    } else if (t < 41536) {               // wcomb[layer][i][0..63]=w2^T, [64..127]=ww^T
        int u = t - 8768;
        int layer = u >> 13;
        int r = u & 8191;
        int i = r >> 7, c = r & 127;
        float v;
        if (c < 64) v = m2w[layer * 4096 + c * 64 + i];
        else        v = wwp[layer * 4096 + (c - 64) * 64 + i];
        wcomb[u] = v;
    } else if (t < 46144) {               // WTy[f][y]: f=2ky(+1) -> cos/sin, y pad->0
        int u = t - 41536;
        int f = u / 144, y = u - f * 144;
        float v = 0.f;
        if (y < HH) {
            int ky = f >> 1;
            int m = (y * ky) % HH;
            double ang = -PI2 * (double)m / (double)HH;
            v = (f & 1) ? (float)sin(ang) : (float)cos(ang);
        }
        WTy[u] = v;
    }
}

// ---- per-layer spectral-weight transpose: WS[kx][ky][i][o] (float2 re/im) ----
__global__ void k_wtrans(const float* __restrict__ sw1, const float* __restrict__ sw2,
                         int layer, float* __restrict__ WS) {
    int d = blockIdx.x * 256 + threadIdx.x;
    int reim = d & 1;
    int o  = (d >> 1) & 63;
    int i  = (d >> 7) & 63;
    int ky = (d >> 13) & 15;
    int kx = (d >> 17) & 31;
    const float* src = (kx < 16) ? sw1 : sw2;
    int kk = kx & 15;
    WS[d] = src[layer * 2097152 + reim * 1048576 + i * 16384 + o * 256 + kk * 16 + ky];
}

// ---- projection into padded X0 ----
__global__ void k_proj(const float* __restrict__ x, const float* __restrict__ pw,
                       const float* __restrict__ pb, float* __restrict__ X0) {
    int t = blockIdx.x * 256 + threadIdx.x;
    int b = t / (CH * CS);
    int r = t - b * (CH * CS);
    int d = r / CS;
    int s = r - d * CS;
    int X = s / XS, Y = s - X * XS;
    float v = 0.f;
    if (X < SS && Y < SS) {
        v = pb[d];
        #pragma unroll
        for (int c = 0; c < 5; c++)
            v += x[((b * 5 + c) * SS + X) * SS + Y] * pw[c * CH + d];
        v += ((float)X * (1.0f / 127.0f)) * pw[5 * CH + d];
        v += ((float)Y * (1.0f / 127.0f)) * pw[6 * CH + d];
    }
    X0[t] = v;
}

// ---- forward DFT along y: coalesced float4 staging + scatter LDS transpose ----
__global__ void __launch_bounds__(256) k_dfty3(const float* __restrict__ X0,
                                               const float2* __restrict__ Wy,
                                               float* __restrict__ Tf) {
    __shared__ float sXT[32 * 260];
    __shared__ float sWy[HH * 32];
    int tid = threadIdx.x;
    int r0b = blockIdx.x * 256;
    int bi0 = r0b / 137;
    int xx0 = r0b - bi0 * 137;
    for (int idx = tid; idx < HH * MM; idx += 256) {
        float2 w = Wy[idx];
        sWy[idx * 2] = w.x;
        sWy[idx * 2 + 1] = w.y;
    }
    int rowg = tid >> 2, kg = tid & 3;
    int r0 = rowg * 4, k0 = kg * 8;
    float acc[4][8];
    #pragma unroll
    for (int a = 0; a < 4; a++)
        #pragma unroll
        for (int c = 0; c < 8; c++) acc[a][c] = 0.f;
    for (int yc = 0; yc < 5; yc++) {
        int y0c = yc * 32;
        int ylen = (y0c + 32 <= HH) ? 32 : (HH - y0c);
        __syncthreads();
        for (int k = 0; k < 8; k++) {
            int idx = k * 256 + tid;
            int r = idx >> 3, q = idx & 7;
            int xx = xx0 + r, bi = bi0;
            if (xx >= 137) { xx -= 137; bi++; }
            if (xx >= 137) { xx -= 137; bi++; }
            int y = y0c + 4 * q;
            size_t off = (size_t)bi * CS + xx * XS + y;
            float4 v;
            if (y + 4 <= HH) {
                v = *(const float4*)&X0[off];
            } else {
                v.x = (y     < HH) ? X0[off]     : 0.f;
                v.y = (y + 1 < HH) ? X0[off + 1] : 0.f;
                v.z = (y + 2 < HH) ? X0[off + 2] : 0.f;
                v.w = (y + 3 < HH) ? X0[off + 3] : 0.f;
            }
            int yy = 4 * q;
            sXT[(yy    ) * 260 + r] = v.x;
            sXT[(yy + 1) * 260 + r] = v.y;
            sXT[(yy + 2) * 260 + r] = v.z;
            sXT[(yy + 3) * 260 + r] = v.w;
        }
        __syncthreads();
        for (int yy = 0; yy < ylen; yy++) {
            int y = y0c + yy;
            float4 wA = *(const float4*)&sWy[y * 32 + k0];
            float4 wB = *(const float4*)&sWy[y * 32 + k0 + 4];
            float4 v  = *(const float4*)&sXT[yy * 260 + r0];
            float wv[8] = {wA.x, wA.y, wA.z, wA.w, wB.x, wB.y, wB.z, wB.w};
            float vv[4] = {v.x, v.y, v.z, v.w};
            #pragma unroll
            for (int a = 0; a < 4; a++)
                #pragma unroll
                for (int c = 0; c < 8; c++) acc[a][c] += vv[a] * wv[c];
        }
    }
    #pragma unroll
    for (int a = 0; a < 4; a++) {
        size_t rb = (size_t)(r0b + r0 + a) * 32 + k0;
        *(float4*)&Tf[rb]     = make_float4(acc[a][0], acc[a][1], acc[a][2], acc[a][3]);
        *(float4*)&Tf[rb + 4] = make_float4(acc[a][4], acc[a][5], acc[a][6], acc[a][7]);
    }
}

// ---- forward DFT along x: LDS-staged per (b,i) ----
__global__ void __launch_bounds__(512) k_dftx2(const float* __restrict__ Tf,
                                               const float2* __restrict__ Wx,
                                               float2* __restrict__ F) {
    __shared__ float sT[HH * 32];
    __shared__ float2 sWx[HH * 32];
    int tid = threadIdx.x;
    int bi = blockIdx.x;
    const float4* tg = (const float4*)(Tf + (size_t)bi * (HH * 32));
    for (int idx = tid; idx < HH * 8; idx += 512) ((float4*)sT)[idx] = tg[idx];
    const float4* wg = (const float4*)Wx;
    for (int idx = tid; idx < HH * 16; idx += 512) ((float4*)sWx)[idx] = wg[idx];
    __syncthreads();
    int ky = tid & 15, kx = tid >> 4;
    float fr = 0.f, fi = 0.f;
    const float2* sT2 = (const float2*)sT;
    #pragma unroll 4
    for (int x = 0; x < HH; x++) {
        float2 t = sT2[x * 16 + ky];
        float2 w = sWx[x * 32 + kx];
        fr += t.x * w.x - t.y * w.y;
        fi += t.x * w.y + t.y * w.x;
    }
    F[(size_t)bi * 512 + tid] = make_float2(fr, fi);
}

// ---- spectral multiply with transposed weights ----
__global__ void __launch_bounds__(256) k_specmul2(const float2* __restrict__ F,
                                                  const float2* __restrict__ WS,
                                                  float2* __restrict__ G) {
    int tid = threadIdx.x;
    int o = tid & 63;
    int kyq = __builtin_amdgcn_readfirstlane(tid >> 6);
    int kx = blockIdx.x;
    int bg = blockIdx.y;
    for (int bq = 0; bq < 2; bq++) {
        int b = bg * 2 + bq;
        float gr[4], gi[4];
        #pragma unroll
        for (int j = 0; j < 4; j++) { gr[j] = 0.f; gi[j] = 0.f; }
        for (int i = 0; i < CH; i++) {
            const float2* Fb = F + ((size_t)(b * CH + i) * KK + kx) * MM + kyq * 4;
            const float2* Wb = WS + ((size_t)(kx * MM + kyq * 4) * CH + i) * CH + o;
            #pragma unroll
            for (int j = 0; j < 4; j++) {
                float2 f = Fb[j];
                float2 w = Wb[(size_t)j * CH * CH];
                gr[j] += f.x * w.x - f.y * w.y;
                gi[j] += f.x * w.y + f.y * w.x;
            }
        }
        float* Gf = (float*)G;
        size_t base = (((size_t)(b * CH + o) * KK + kx) * MM + kyq * 4) * 2;
        *(float4*)&Gf[base]     = make_float4(gr[0], gi[0], gr[1], gi[1]);
        *(float4*)&Gf[base + 4] = make_float4(gr[2], gi[2], gr[3], gi[3]);
    }
}

// ---- mode-space mlp1 ----
__global__ void __launch_bounds__(128) k_mlp1m(const float* __restrict__ Gf,
                                               const float* __restrict__ m1w, int layer,
                                               float* __restrict__ G2f) {
    __shared__ float sG[64 * 64];
    __shared__ float sM[64 * 68];
    int tid = threadIdx.x;
    int b = blockIdx.y;
    int c0b = blockIdx.x * 64;
    for (int idx = tid; idx < 4096; idx += 128) {
        int o = idx >> 6, c = idx & 63;
        sG[idx] = Gf[(size_t)(b * CH + o) * 1024 + c0b + c];
    }
    for (int idx = tid; idx < 4096; idx += 128) {
        int p = idx >> 6, o = idx & 63;
        sM[o * 68 + p] = m1w[layer * 4096 + p * 64 + o];
    }
    __syncthreads();
    int cg = tid & 15, pg = tid >> 4;
    int c0 = cg * 4, p0 = pg * 8;
    float acc[8][4];
    #pragma unroll
    for (int a = 0; a < 8; a++)
        #pragma unroll
        for (int c = 0; c < 4; c++) acc[a][c] = 0.f;
    for (int o = 0; o < CH; o++) {
        float4 wA = *(const float4*)&sM[o * 68 + p0];
        float4 wB = *(const float4*)&sM[o * 68 + p0 + 4];
        float4 v  = *(const float4*)&sG[o * 64 + c0];
        float wv[8] = {wA.x, wA.y, wA.z, wA.w, wB.x, wB.y, wB.z, wB.w};
        float vv[4] = {v.x, v.y, v.z, v.w};
        #pragma unroll
        for (int a = 0; a < 8; a++)
            #pragma unroll
            for (int c = 0; c < 4; c++) acc[a][c] += wv[a] * vv[c];
    }
    #pragma unroll
    for (int a = 0; a < 8; a++)
        *(float4*)&G2f[(size_t)(b * CH + p0 + a) * 1024 + c0b + c0] =
            make_float4(acc[a][0], acc[a][1], acc[a][2], acc[a][3]);
}

// ---- inverse DFT along x: LDS-staged per (b,o) ----
__global__ void __launch_bounds__(256) k_invx2(const float2* __restrict__ G2,
                                               const float2* __restrict__ Wx,
                                               float2* __restrict__ Hh) {
    __shared__ float2 sG[512];
    __shared__ float2 sWx[HH * 32];
    int tid = threadIdx.x;
    int bo = blockIdx.x;
    const float4* gg = (const float4*)(G2 + (size_t)bo * 512);
    if (tid < 256) ((float4*)sG)[tid] = gg[tid];
    const float4* wg = (const float4*)Wx;
    for (int idx = tid; idx < HH * 16; idx += 256) ((float4*)sWx)[idx] = wg[idx];
    __syncthreads();
    for (int it = 0; it < 9; it++) {
        int item = it * 256 + tid;
        if (item >= HH * 16) break;
        int x = item >> 4, ky = item & 15;
        float hr = 0.f, hi = 0.f;
        #pragma unroll 4
        for (int kx = 0; kx < KK; kx++) {
            float2 g = sG[kx * 16 + ky];
            float2 w = sWx[x * 32 + kx];
            hr += g.x * w.x + g.y * w.y;
            hi += g.y * w.x - g.x * w.y;
        }
        float sc = (ky == 0 ? 1.0f : 2.0f) / 18769.0f;
        Hh[(size_t)bo * (HH * 16) + item] = make_float2(hr * sc, hi * sc);
    }
}

// ---- inverse-y as GEMM + bias + gelu: X1[row=(bo,x)][y] ----
// rows: Hh float-view [row][32], weights WTy[32][144]; 56 rows/block
__global__ void __launch_bounds__(256) k_invyg(const float* __restrict__ Hhf,
                                               const float* __restrict__ WTy,
                                               const float* __restrict__ m1b, int layer,
                                               float* __restrict__ X1) {
    __shared__ float sHT[32 * 60];    // [k][r] transposed rows, 7.5KB
    __shared__ float sW[32 * 144];    // [k][y] 18KB
    int tid = threadIdx.x;
    int row0 = blockIdx.x * 56;
    // stage rows (transposed scatter)
    for (int idx = tid; idx < 512; idx += 256) {
        int r = idx >> 3, q = idx & 7;
        int row = row0 + r;
        float4 v = make_float4(0.f, 0.f, 0.f, 0.f);
        if (r < 56 && row < NROW)
            v = *(const float4*)&Hhf[(size_t)row * 32 + q * 4];
        sHT[(4 * q + 0) * 60 + r] = v.x;
        sHT[(4 * q + 1) * 60 + r] = v.y;
        sHT[(4 * q + 2) * 60 + r] = v.z;
        sHT[(4 * q + 3) * 60 + r] = v.w;
    }
    for (int idx = tid; idx < 1152; idx += 256)
        ((float4*)sW)[idx] = ((const float4*)WTy)[idx];
    __syncthreads();
    if (tid >= 252) return;
    int rg = tid / 18, cg = tid - rg * 18;
    int r0 = rg * 4, c0 = cg * 8;
    float acc[4][8];
    #pragma unroll
    for (int a = 0; a < 4; a++)
        #pragma unroll
        for (int c = 0; c < 8; c++) acc[a][c] = 0.f;
    for (int k = 0; k < 32; k++) {
        float4 rv = *(const float4*)&sHT[k * 60 + r0];
        float4 wA = *(const float4*)&sW[k * 144 + c0];
        float4 wB = *(const float4*)&sW[k * 144 + c0 + 4];
        float rr[4] = {rv.x, rv.y, rv.z, rv.w};
        float wv[8] = {wA.x, wA.y, wA.z, wA.w, wB.x, wB.y, wB.z, wB.w};
        #pragma unroll
        for (int a = 0; a < 4; a++)
            #pragma unroll
            for (int c = 0; c < 8; c++) acc[a][c] += rr[a] * wv[c];
    }
    #pragma unroll
    for (int a = 0; a < 4; a++) {
        int row = row0 + r0 + a;
        if (row >= NROW) continue;
        unsigned bo = (unsigned)row / 137u;
        int x = row - (int)bo * 137;
        int o = bo & 63;
        float b1v = m1b[layer * CH + o];
        float g[8];
        #pragma unroll
        for (int c = 0; c < 8; c++) g[c] = gelu_f(acc[a][c] + b1v);
        size_t base = (size_t)bo * CS + x * XS;
        if (c0 + 8 <= HH) {
            *(float4*)&X1[base + c0]     = make_float4(g[0], g[1], g[2], g[3]);
            *(float4*)&X1[base + c0 + 4] = make_float4(g[4], g[5], g[6], g[7]);
        } else {
            #pragma unroll
            for (int c = 0; c < 8; c++)
                if (c0 + c < HH) X1[base + c0 + c] = g[c];
        }
    }
}

// ---- tail: X0 = gelu(w2.X1 + ww.X0 + b2 + wb), 2-pass LDS micro-GEMM, in-place ----
__global__ void __launch_bounds__(256) k_tail3(float* __restrict__ X0,
    const float* __restrict__ X1, const float* __restrict__ wcomb,
    const float* __restrict__ b2, const float* __restrict__ wb, int layer) {
    __shared__ float sV[CH * 132];   // 33.8KB
    __shared__ float sW[CH * 68];    // 17.4KB
    int tid = threadIdx.x;
    int b = blockIdx.y;
    int s0 = blockIdx.x * 128;
    int og = tid & 15, pg = tid >> 4;
    int o0 = og * 4, p0 = pg * 8;
    float acc[4][8];
    #pragma unroll
    for (int a = 0; a < 4; a++)
        #pragma unroll
        for (int c = 0; c < 8; c++) acc[a][c] = 0.f;
    const float* wl = wcomb + layer * 8192;

    #pragma unroll
    for (int pass = 0; pass < 2; pass++) {
        const float* src = pass ? X0 : X1;
        for (int idx = tid; idx < 2048; idx += 256) {
            int i = idx >> 5, p4 = (idx & 31) * 4;
            float4 v = make_float4(0.f, 0.f, 0.f, 0.f);
            int s = s0 + p4;
            if (s + 4 <= CS) v = *(const float4*)&src[(size_t)(b * CH + i) * CS + s];
            *(float4*)&sV[i * 132 + p4] = v;
        }
        for (int idx = tid; idx < 4096; idx += 256) {
            int i = idx >> 6, o = idx & 63;
            sW[i * 68 + o] = wl[i * 128 + (pass ? 64 + o : o)];
        }
        __syncthreads();
        for (int i = 0; i < CH; i++) {
            float4 w  = *(const float4*)&sW[i * 68 + o0];
            float4 vA = *(const float4*)&sV[i * 132 + p0];
            float4 vB = *(const float4*)&sV[i * 132 + p0 + 4];
            float wv[4] = {w.x, w.y, w.z, w.w};
            float vv[8] = {vA.x, vA.y, vA.z, vA.w, vB.x, vB.y, vB.z, vB.w};
            #pragma unroll
            for (int a = 0; a < 4; a++)
                #pragma unroll
                for (int c = 0; c < 8; c++) acc[a][c] += wv[a] * vv[c];
        }
        __syncthreads();
    }
    #pragma unroll
    for (int a = 0; a < 4; a++) {
        float bia = b2[layer * CH + o0 + a] + wb[layer * CH + o0 + a];
        float g[8];
        #pragma unroll
        for (int c = 0; c < 8; c++) g[c] = gelu_f(acc[a][c] + bia);
        size_t rowb = (size_t)(b * CH + o0 + a) * CS + s0 + p0;
        if (s0 + p0 + 4 <= CS)
            *(float4*)&X0[rowb] = make_float4(g[0], g[1], g[2], g[3]);
        if (s0 + p0 + 8 <= CS)
            *(float4*)&X0[rowb + 4] = make_float4(g[4], g[5], g[6], g[7]);
    }
}

// ---- final head: LDS micro-GEMM ----
__global__ void __launch_bounds__(256) k_final5(const float* __restrict__ X0,
    const float* __restrict__ q1w, const float* __restrict__ q1b,
    const float* __restrict__ q2w, const float* __restrict__ q2b,
    float* __restrict__ out) {
    __shared__ float sV[CH * 132];
    __shared__ float sW[CH * 68];
    int tid = threadIdx.x;
    int b = blockIdx.y;
    int X = blockIdx.x;
    for (int k = 0; k < 8; k++) {
        int idx = k * 256 + tid;
        int i = idx >> 5, yq = idx & 31;
        *(float4*)&sV[i * 132 + yq * 4] =
            *(const float4*)&X0[(size_t)(b * CH + i) * CS + X * XS + yq * 4];
    }
    int hg = tid & 15, yg = tid >> 4;
    int h0 = hg * 4, y0 = yg * 8;
    float qacc[8];
    #pragma unroll
    for (int c = 0; c < 8; c++) qacc[c] = 0.f;
    for (int hc = 0; hc < 4; hc++) {
        __syncthreads();
        for (int idx = tid; idx < 4096; idx += 256) {
            int h = idx >> 6, i = idx & 63;
            sW[i * 68 + h] = q1w[(hc * 64 + h) * 64 + i];
        }
        __syncthreads();
        float acc[4][8];
        #pragma unroll
        for (int a = 0; a < 4; a++)
            #pragma unroll
            for (int c = 0; c < 8; c++) acc[a][c] = 0.f;
        for (int i = 0; i < CH; i++) {
            float4 w  = *(const float4*)&sW[i * 68 + h0];
            float4 vA = *(const float4*)&sV[i * 132 + y0];
            float4 vB = *(const float4*)&sV[i * 132 + y0 + 4];
            float wv[4] = {w.x, w.y, w.z, w.w};
            float vv[8] = {vA.x, vA.y, vA.z, vA.w, vB.x, vB.y, vB.z, vB.w};
            #pragma unroll
            for (int a = 0; a < 4; a++)
                #pragma unroll
                for (int c = 0; c < 8; c++) acc[a][c] += wv[a] * vv[c];
        }
        #pragma unroll
        for (int a = 0; a < 4; a++) {
            int h = hc * 64 + h0 + a;
            float qb = q1b[h], q2v = q2w[h];
            #pragma unroll
            for (int c = 0; c < 8; c++)
                qacc[c] += q2v * gelu_f(acc[a][c] + qb);
        }
    }
    __syncthreads();
    float* sRed = sW;
    *(float4*)&sRed[hg * 132 + y0]     = make_float4(qacc[0], qacc[1], qacc[2], qacc[3]);
    *(float4*)&sRed[hg * 132 + y0 + 4] = make_float4(qacc[4], qacc[5], qacc[6], qacc[7]);
    __syncthreads();
    if (tid < 128) {
        float r = q2b[0];
        #pragma unroll
        for (int g = 0; g < 16; g++) r += sRed[g * 132 + tid];
        out[(b * SS + X) * SS + tid] = r;
    }
}

extern "C" void kernel_launch(void* const* d_in, const int* in_sizes, int n_in,
                              void* d_out, int out_size, void* d_ws, size_t ws_size,
                              hipStream_t stream) {
    const float* x   = (const float*)d_in[0];
    const float* p_w = (const float*)d_in[1];
    const float* p_b = (const float*)d_in[2];
    const float* sw1 = (const float*)d_in[3];
    const float* sw2 = (const float*)d_in[4];
    const float* m1w = (const float*)d_in[5];
    const float* m1b = (const float*)d_in[6];
    const float* m2w = (const float*)d_in[7];
    const float* m2b = (const float*)d_in[8];
    const float* wwp = (const float*)d_in[9];
    const float* wbp = (const float*)d_in[10];
    const float* q1w = (const float*)d_in[11];
    const float* q1b = (const float*)d_in[12];
    const float* q2w = (const float*)d_in[13];
    const float* q2b = (const float*)d_in[14];

    float* ws = (float*)d_ws;
    float*  X0   = ws;                                   // 19,640,320 f
    float*  X1   = X0 + (size_t)BB * CH * CS;            // 19,640,320 f (WS aliases base)
    float*  WS   = X1;                                   // 4,194,304 f (dead before X1 use)
    float*  Tf   = X1 + (size_t)BB * CH * CS;            // 4,489,216 f (T / Hh)
    float2* F    = (float2*)(Tf + (size_t)NROW * 32);    // 524,288 f2 (F / G2)
    float2* G    = F + (size_t)524288;
    float2* Wy   = G + (size_t)524288;
    float2* Wx   = Wy + 2192;
    float2* WyT  = Wx + 4384;
    float*  wcomb = (float*)(WyT + 2192);                // 32768 f
    float*  WTy  = wcomb + 32768;                        // 4608 f

    k_init<<<181, 256, 0, stream>>>(Wy, Wx, WyT, wcomb, WTy, m2w, wwp);
    k_proj<<<(BB * CH * CS) / 256, 256, 0, stream>>>(x, p_w, p_b, X0);
    for (int layer = 0; layer < NL; layer++) {
        k_wtrans<<<16384, 256, 0, stream>>>(sw1, sw2, layer, WS);
        k_dfty3<<<548, 256, 0, stream>>>(X0, Wy, Tf);
        k_dftx2<<<1024, 512, 0, stream>>>(Tf, Wx, F);
        k_specmul2<<<dim3(32, 8), 256, 0, stream>>>(F, (const float2*)WS, G);
        k_mlp1m<<<dim3(16, BB), 128, 0, stream>>>((const float*)G, m1w, layer, (float*)F);
        k_invx2<<<1024, 256, 0, stream>>>(F, Wx, (float2*)Tf);
        k_invyg<<<(NROW + 55) / 56, 256, 0, stream>>>(Tf, WTy, m1b, layer, X1);
        k_tail3<<<dim3((CS + 127) / 128, BB), 256, 0, stream>>>(X0, X1, wcomb, m2b, wbp, layer);
    }
    k_final5<<<dim3(SS, BB), 256, 0, stream>>>(X0, q1w, q1b, q2w, q2b, (float*)d_out);
}

// Round 7
// 1376.055 us; speedup vs baseline: 1.2480x; 1.2480x over previous
//
#include <hip/hip_runtime.h>
#include <math.h>

#define BB 16
#define CH 64
#define SS 128
#define HH 137
#define XS 140            // padded x-stride (16B-aligned float4)
#define CS (137 * 140)    // per-channel stride = 19180
#define MM 16
#define KK 32
#define NL 4
#define NROW 140288       // BB*CH*HH rows of (bo,x)

__device__ __forceinline__ float gelu_f(float x) {
    return 0.5f * x * (1.0f + erff(x * 0.70710678118654752440f));
}

// ---- init: twiddles + fused tail weights + WTy (32x144 inv-y GEMM weights) ----
__global__ void k_init(float2* __restrict__ Wy, float2* __restrict__ Wx,
                       float2* __restrict__ WyT, float* __restrict__ wcomb,
                       float* __restrict__ WTy,
                       const float* __restrict__ m2w, const float* __restrict__ wwp) {
    int t = blockIdx.x * 256 + threadIdx.x;
    const double PI2 = 6.283185307179586476925286766559;
    if (t < 2192) {                       // Wy[y*16+ky]
        int y = t >> 4, k = t & 15;
        int m = (y * k) % HH;
        double ang = -PI2 * (double)m / (double)HH;
        Wy[t] = make_float2((float)cos(ang), (float)sin(ang));
    } else if (t < 6576) {                // Wx[x*32+ki]
        int u = t - 2192;
        int x = u >> 5, ki = u & 31;
        int K = (ki < 16) ? ki : (105 + ki);
        int m = (x * K) % HH;
        double ang = -PI2 * (double)m / (double)HH;
        Wx[u] = make_float2((float)cos(ang), (float)sin(ang));
    } else if (t < 8768) {                // WyT[ky*137+y]
        int u = t - 6576;
        int ky = u / 137, y = u - ky * 137;
        int m = (y * ky) % HH;
        double ang = -PI2 * (double)m / (double)HH;
        WyT[u] = make_float2((float)cos(ang), (float)sin(ang));
    } else if (t < 41536) {               // wcomb[layer][i][0..63]=w2^T, [64..127]=ww^T
        int u = t - 8768;
        int layer = u >> 13;
        int r = u & 8191;
        int i = r >> 7, c = r & 127;
        float v;
        if (c < 64) v = m2w[layer * 4096 + c * 64 + i];
        else        v = wwp[layer * 4096 + (c - 64) * 64 + i];
        wcomb[u] = v;
    } else if (t < 46144) {               // WTy[f][y]: f=2ky(+1) -> cos/sin, y pad->0
        int u = t - 41536;
        int f = u / 144, y = u - f * 144;
        float v = 0.f;
        if (y < HH) {
            int ky = f >> 1;
            int m = (y * ky) % HH;
            double ang = -PI2 * (double)m / (double)HH;
            v = (f & 1) ? (float)sin(ang) : (float)cos(ang);
        }
        WTy[u] = v;
    }
}

// ---- per-layer spectral-weight transpose: WS[kx][ky][i][o] (float2 re/im) ----
__global__ void k_wtrans(const float* __restrict__ sw1, const float* __restrict__ sw2,
                         int layer, float* __restrict__ WS) {
    int d = blockIdx.x * 256 + threadIdx.x;
    int reim = d & 1;
    int o  = (d >> 1) & 63;
    int i  = (d >> 7) & 63;
    int ky = (d >> 13) & 15;
    int kx = (d >> 17) & 31;
    const float* src = (kx < 16) ? sw1 : sw2;
    int kk = kx & 15;
    WS[d] = src[layer * 2097152 + reim * 1048576 + i * 16384 + o * 256 + kk * 16 + ky];
}

// ---- projection into padded X0 ----
__global__ void k_proj(const float* __restrict__ x, const float* __restrict__ pw,
                       const float* __restrict__ pb, float* __restrict__ X0) {
    int t = blockIdx.x * 256 + threadIdx.x;
    int b = t / (CH * CS);
    int r = t - b * (CH * CS);
    int d = r / CS;
    int s = r - d * CS;
    int X = s / XS, Y = s - X * XS;
    float v = 0.f;
    if (X < SS && Y < SS) {
        v = pb[d];
        #pragma unroll
        for (int c = 0; c < 5; c++)
            v += x[((b * 5 + c) * SS + X) * SS + Y] * pw[c * CH + d];
        v += ((float)X * (1.0f / 127.0f)) * pw[5 * CH + d];
        v += ((float)Y * (1.0f / 127.0f)) * pw[6 * CH + d];
    }
    X0[t] = v;
}

// ---- forward DFT along y: coalesced float4 staging + scatter LDS transpose ----
__global__ void __launch_bounds__(256) k_dfty3(const float* __restrict__ X0,
                                               const float2* __restrict__ Wy,
                                               float* __restrict__ Tf) {
    __shared__ float sXT[32 * 260];
    __shared__ float sWy[HH * 32];
    int tid = threadIdx.x;
    int r0b = blockIdx.x * 256;
    int bi0 = r0b / 137;
    int xx0 = r0b - bi0 * 137;
    for (int idx = tid; idx < HH * MM; idx += 256) {
        float2 w = Wy[idx];
        sWy[idx * 2] = w.x;
        sWy[idx * 2 + 1] = w.y;
    }
    int rowg = tid >> 2, kg = tid & 3;
    int r0 = rowg * 4, k0 = kg * 8;
    float acc[4][8];
    #pragma unroll
    for (int a = 0; a < 4; a++)
        #pragma unroll
        for (int c = 0; c < 8; c++) acc[a][c] = 0.f;
    for (int yc = 0; yc < 5; yc++) {
        int y0c = yc * 32;
        int ylen = (y0c + 32 <= HH) ? 32 : (HH - y0c);
        __syncthreads();
        for (int k = 0; k < 8; k++) {
            int idx = k * 256 + tid;
            int r = idx >> 3, q = idx & 7;
            int xx = xx0 + r, bi = bi0;
            if (xx >= 137) { xx -= 137; bi++; }
            if (xx >= 137) { xx -= 137; bi++; }
            int y = y0c + 4 * q;
            size_t off = (size_t)bi * CS + xx * XS + y;
            float4 v;
            if (y + 4 <= HH) {
                v = *(const float4*)&X0[off];
            } else {
                v.x = (y     < HH) ? X0[off]     : 0.f;
                v.y = (y + 1 < HH) ? X0[off + 1] : 0.f;
                v.z = (y + 2 < HH) ? X0[off + 2] : 0.f;
                v.w = (y + 3 < HH) ? X0[off + 3] : 0.f;
            }
            int yy = 4 * q;
            sXT[(yy    ) * 260 + r] = v.x;
            sXT[(yy + 1) * 260 + r] = v.y;
            sXT[(yy + 2) * 260 + r] = v.z;
            sXT[(yy + 3) * 260 + r] = v.w;
        }
        __syncthreads();
        for (int yy = 0; yy < ylen; yy++) {
            int y = y0c + yy;
            float4 wA = *(const float4*)&sWy[y * 32 + k0];
            float4 wB = *(const float4*)&sWy[y * 32 + k0 + 4];
            float4 v  = *(const float4*)&sXT[yy * 260 + r0];
            float wv[8] = {wA.x, wA.y, wA.z, wA.w, wB.x, wB.y, wB.z, wB.w};
            float vv[4] = {v.x, v.y, v.z, v.w};
            #pragma unroll
            for (int a = 0; a < 4; a++)
                #pragma unroll
                for (int c = 0; c < 8; c++) acc[a][c] += vv[a] * wv[c];
        }
    }
    #pragma unroll
    for (int a = 0; a < 4; a++) {
        size_t rb = (size_t)(r0b + r0 + a) * 32 + k0;
        *(float4*)&Tf[rb]     = make_float4(acc[a][0], acc[a][1], acc[a][2], acc[a][3]);
        *(float4*)&Tf[rb + 4] = make_float4(acc[a][4], acc[a][5], acc[a][6], acc[a][7]);
    }
}

// ---- forward DFT along x: LDS-staged per (b,i) ----
__global__ void __launch_bounds__(512) k_dftx2(const float* __restrict__ Tf,
                                               const float2* __restrict__ Wx,
                                               float2* __restrict__ F) {
    __shared__ float sT[HH * 32];
    __shared__ float2 sWx[HH * 32];
    int tid = threadIdx.x;
    int bi = blockIdx.x;
    const float4* tg = (const float4*)(Tf + (size_t)bi * (HH * 32));
    for (int idx = tid; idx < HH * 8; idx += 512) ((float4*)sT)[idx] = tg[idx];
    const float4* wg = (const float4*)Wx;
    for (int idx = tid; idx < HH * 16; idx += 512) ((float4*)sWx)[idx] = wg[idx];
    __syncthreads();
    int ky = tid & 15, kx = tid >> 4;
    float fr = 0.f, fi = 0.f;
    const float2* sT2 = (const float2*)sT;
    #pragma unroll 4
    for (int x = 0; x < HH; x++) {
        float2 t = sT2[x * 16 + ky];
        float2 w = sWx[x * 32 + kx];
        fr += t.x * w.x - t.y * w.y;
        fi += t.x * w.y + t.y * w.x;
    }
    F[(size_t)bi * 512 + tid] = make_float2(fr, fi);
}

// ---- spectral multiply with transposed weights ----
__global__ void __launch_bounds__(256) k_specmul2(const float2* __restrict__ F,
                                                  const float2* __restrict__ WS,
                                                  float2* __restrict__ G) {
    int tid = threadIdx.x;
    int o = tid & 63;
    int kyq = __builtin_amdgcn_readfirstlane(tid >> 6);
    int kx = blockIdx.x;
    int bg = blockIdx.y;
    for (int bq = 0; bq < 2; bq++) {
        int b = bg * 2 + bq;
        float gr[4], gi[4];
        #pragma unroll
        for (int j = 0; j < 4; j++) { gr[j] = 0.f; gi[j] = 0.f; }
        for (int i = 0; i < CH; i++) {
            const float2* Fb = F + ((size_t)(b * CH + i) * KK + kx) * MM + kyq * 4;
            const float2* Wb = WS + ((size_t)(kx * MM + kyq * 4) * CH + i) * CH + o;
            #pragma unroll
            for (int j = 0; j < 4; j++) {
                float2 f = Fb[j];
                float2 w = Wb[(size_t)j * CH * CH];
                gr[j] += f.x * w.x - f.y * w.y;
                gi[j] += f.x * w.y + f.y * w.x;
            }
        }
        float* Gf = (float*)G;
        size_t base = (((size_t)(b * CH + o) * KK + kx) * MM + kyq * 4) * 2;
        *(float4*)&Gf[base]     = make_float4(gr[0], gi[0], gr[1], gi[1]);
        *(float4*)&Gf[base + 4] = make_float4(gr[2], gi[2], gr[3], gi[3]);
    }
}

// ---- mode-space mlp1 ----
__global__ void __launch_bounds__(128) k_mlp1m(const float* __restrict__ Gf,
                                               const float* __restrict__ m1w, int layer,
                                               float* __restrict__ G2f) {
    __shared__ float sG[64 * 64];
    __shared__ float sM[64 * 68];
    int tid = threadIdx.x;
    int b = blockIdx.y;
    int c0b = blockIdx.x * 64;
    for (int idx = tid; idx < 4096; idx += 128) {
        int o = idx >> 6, c = idx & 63;
        sG[idx] = Gf[(size_t)(b * CH + o) * 1024 + c0b + c];
    }
    for (int idx = tid; idx < 4096; idx += 128) {
        int p = idx >> 6, o = idx & 63;
        sM[o * 68 + p] = m1w[layer * 4096 + p * 64 + o];
    }
    __syncthreads();
    int cg = tid & 15, pg = tid >> 4;
    int c0 = cg * 4, p0 = pg * 8;
    float acc[8][4];
    #pragma unroll
    for (int a = 0; a < 8; a++)
        #pragma unroll
        for (int c = 0; c < 4; c++) acc[a][c] = 0.f;
    for (int o = 0; o < CH; o++) {
        float4 wA = *(const float4*)&sM[o * 68 + p0];
        float4 wB = *(const float4*)&sM[o * 68 + p0 + 4];
        float4 v  = *(const float4*)&sG[o * 64 + c0];
        float wv[8] = {wA.x, wA.y, wA.z, wA.w, wB.x, wB.y, wB.z, wB.w};
        float vv[4] = {v.x, v.y, v.z, v.w};
        #pragma unroll
        for (int a = 0; a < 8; a++)
            #pragma unroll
            for (int c = 0; c < 4; c++) acc[a][c] += wv[a] * vv[c];
    }
    #pragma unroll
    for (int a = 0; a < 8; a++)
        *(float4*)&G2f[(size_t)(b * CH + p0 + a) * 1024 + c0b + c0] =
            make_float4(acc[a][0], acc[a][1], acc[a][2], acc[a][3]);
}

// ---- inverse DFT along x: LDS-staged per (b,o) ----
__global__ void __launch_bounds__(256) k_invx2(const float2* __restrict__ G2,
                                               const float2* __restrict__ Wx,
                                               float2* __restrict__ Hh) {
    __shared__ float2 sG[512];
    __shared__ float2 sWx[HH * 32];
    int tid = threadIdx.x;
    int bo = blockIdx.x;
    const float4* gg = (const float4*)(G2 + (size_t)bo * 512);
    if (tid < 256) ((float4*)sG)[tid] = gg[tid];
    const float4* wg = (const float4*)Wx;
    for (int idx = tid; idx < HH * 16; idx += 256) ((float4*)sWx)[idx] = wg[idx];
    __syncthreads();
    for (int it = 0; it < 9; it++) {
        int item = it * 256 + tid;
        if (item >= HH * 16) break;
        int x = item >> 4, ky = item & 15;
        float hr = 0.f, hi = 0.f;
        #pragma unroll 4
        for (int kx = 0; kx < KK; kx++) {
            float2 g = sG[kx * 16 + ky];
            float2 w = sWx[x * 32 + kx];
            hr += g.x * w.x + g.y * w.y;
            hi += g.y * w.x - g.x * w.y;
        }
        float sc = (ky == 0 ? 1.0f : 2.0f) / 18769.0f;
        Hh[(size_t)bo * (HH * 16) + item] = make_float2(hr * sc, hi * sc);
    }
}

// ---- inverse-y, register-A micro-GEMM per (b,x): X1[b][i][x][y] = gelu(invy + b1) ----
// lane = i (channel); A (32 K-values) in registers; W broadcast from LDS.
__global__ void __launch_bounds__(256) k_invy4(const float* __restrict__ Hhf,
                                               const float* __restrict__ WTy,
                                               const float* __restrict__ m1b, int layer,
                                               float* __restrict__ X1) {
    __shared__ float sHT[32 * 65];    // [k][i] transposed, stride 65 -> conflict-free
    __shared__ float sWy[32 * 144];   // [k][y] 18.4KB
    int tid = threadIdx.x;
    int x = blockIdx.x;
    int b = blockIdx.y;
    // stage Hh rows for all 64 channels at this (b,x): 512 float4, transposed scatter
    for (int idx = tid; idx < 512; idx += 256) {
        int i = idx >> 3, q = idx & 7;
        float4 v = *(const float4*)&Hhf[((size_t)(b * CH + i) * HH + x) * 32 + q * 4];
        sHT[(4 * q + 0) * 65 + i] = v.x;
        sHT[(4 * q + 1) * 65 + i] = v.y;
        sHT[(4 * q + 2) * 65 + i] = v.z;
        sHT[(4 * q + 3) * 65 + i] = v.w;
    }
    for (int idx = tid; idx < 1152; idx += 256)
        ((float4*)sWy)[idx] = ((const float4*)WTy)[idx];
    __syncthreads();
    int i = tid & 63;
    int wv = tid >> 6;                // wave id 0..3 (wave-uniform)
    float a[32];
    #pragma unroll
    for (int k = 0; k < 32; k++) a[k] = sHT[k * 65 + i];
    float b1v = m1b[layer * CH + i];
    size_t obase = (size_t)(b * CH + i) * CS + x * XS;
    for (int yc = 0; yc < 5; yc++) {
        int y0 = yc * 32 + wv * 8;
        if (y0 >= HH) continue;       // wave-uniform skip
        float acc[8];
        #pragma unroll
        for (int c = 0; c < 8; c++) acc[c] = 0.f;
        #pragma unroll 8
        for (int k = 0; k < 32; k++) {
            float4 wA = *(const float4*)&sWy[k * 144 + y0];
            float4 wB = *(const float4*)&sWy[k * 144 + y0 + 4];
            float av = a[k];
            acc[0] += av * wA.x; acc[1] += av * wA.y;
            acc[2] += av * wA.z; acc[3] += av * wA.w;
            acc[4] += av * wB.x; acc[5] += av * wB.y;
            acc[6] += av * wB.z; acc[7] += av * wB.w;
        }
        float g[8];
        #pragma unroll
        for (int c = 0; c < 8; c++) g[c] = gelu_f(acc[c] + b1v);
        if (y0 + 8 <= HH) {
            *(float4*)&X1[obase + y0]     = make_float4(g[0], g[1], g[2], g[3]);
            *(float4*)&X1[obase + y0 + 4] = make_float4(g[4], g[5], g[6], g[7]);
        } else {
            #pragma unroll
            for (int c = 0; c < 8; c++)
                if (y0 + c < HH) X1[obase + y0 + c] = g[c];
        }
    }
}

// ---- tail: X0 = gelu(w2.X1 + ww.X0 + b2 + wb), 2-pass LDS micro-GEMM, in-place ----
__global__ void __launch_bounds__(256) k_tail3(float* __restrict__ X0,
    const float* __restrict__ X1, const float* __restrict__ wcomb,
    const float* __restrict__ b2, const float* __restrict__ wb, int layer) {
    __shared__ float sV[CH * 132];   // 33.8KB
    __shared__ float sW[CH * 68];    // 17.4KB
    int tid = threadIdx.x;
    int b = blockIdx.y;
    int s0 = blockIdx.x * 128;
    int og = tid & 15, pg = tid >> 4;
    int o0 = og * 4, p0 = pg * 8;
    float acc[4][8];
    #pragma unroll
    for (int a = 0; a < 4; a++)
        #pragma unroll
        for (int c = 0; c < 8; c++) acc[a][c] = 0.f;
    const float* wl = wcomb + layer * 8192;

    #pragma unroll
    for (int pass = 0; pass < 2; pass++) {
        const float* src = pass ? X0 : X1;
        for (int idx = tid; idx < 2048; idx += 256) {
            int i = idx >> 5, p4 = (idx & 31) * 4;
            float4 v = make_float4(0.f, 0.f, 0.f, 0.f);
            int s = s0 + p4;
            if (s + 4 <= CS) v = *(const float4*)&src[(size_t)(b * CH + i) * CS + s];
            *(float4*)&sV[i * 132 + p4] = v;
        }
        for (int idx = tid; idx < 4096; idx += 256) {
            int i = idx >> 6, o = idx & 63;
            sW[i * 68 + o] = wl[i * 128 + (pass ? 64 + o : o)];
        }
        __syncthreads();
        for (int i = 0; i < CH; i++) {
            float4 w  = *(const float4*)&sW[i * 68 + o0];
            float4 vA = *(const float4*)&sV[i * 132 + p0];
            float4 vB = *(const float4*)&sV[i * 132 + p0 + 4];
            float wv[4] = {w.x, w.y, w.z, w.w};
            float vv[8] = {vA.x, vA.y, vA.z, vA.w, vB.x, vB.y, vB.z, vB.w};
            #pragma unroll
            for (int a = 0; a < 4; a++)
                #pragma unroll
                for (int c = 0; c < 8; c++) acc[a][c] += wv[a] * vv[c];
        }
        __syncthreads();
    }
    #pragma unroll
    for (int a = 0; a < 4; a++) {
        float bia = b2[layer * CH + o0 + a] + wb[layer * CH + o0 + a];
        float g[8];
        #pragma unroll
        for (int c = 0; c < 8; c++) g[c] = gelu_f(acc[a][c] + bia);
        size_t rowb = (size_t)(b * CH + o0 + a) * CS + s0 + p0;
        if (s0 + p0 + 4 <= CS)
            *(float4*)&X0[rowb] = make_float4(g[0], g[1], g[2], g[3]);
        if (s0 + p0 + 8 <= CS)
            *(float4*)&X0[rowb + 4] = make_float4(g[4], g[5], g[6], g[7]);
    }
}

// ---- final head: LDS micro-GEMM ----
__global__ void __launch_bounds__(256) k_final5(const float* __restrict__ X0,
    const float* __restrict__ q1w, const float* __restrict__ q1b,
    const float* __restrict__ q2w, const float* __restrict__ q2b,
    float* __restrict__ out) {
    __shared__ float sV[CH * 132];
    __shared__ float sW[CH * 68];
    int tid = threadIdx.x;
    int b = blockIdx.y;
    int X = blockIdx.x;
    for (int k = 0; k < 8; k++) {
        int idx = k * 256 + tid;
        int i = idx >> 5, yq = idx & 31;
        *(float4*)&sV[i * 132 + yq * 4] =
            *(const float4*)&X0[(size_t)(b * CH + i) * CS + X * XS + yq * 4];
    }
    int hg = tid & 15, yg = tid >> 4;
    int h0 = hg * 4, y0 = yg * 8;
    float qacc[8];
    #pragma unroll
    for (int c = 0; c < 8; c++) qacc[c] = 0.f;
    for (int hc = 0; hc < 4; hc++) {
        __syncthreads();
        for (int idx = tid; idx < 4096; idx += 256) {
            int h = idx >> 6, i = idx & 63;
            sW[i * 68 + h] = q1w[(hc * 64 + h) * 64 + i];
        }
        __syncthreads();
        float acc[4][8];
        #pragma unroll
        for (int a = 0; a < 4; a++)
            #pragma unroll
            for (int c = 0; c < 8; c++) acc[a][c] = 0.f;
        for (int i = 0; i < CH; i++) {
            float4 w  = *(const float4*)&sW[i * 68 + h0];
            float4 vA = *(const float4*)&sV[i * 132 + y0];
            float4 vB = *(const float4*)&sV[i * 132 + y0 + 4];
            float wv[4] = {w.x, w.y, w.z, w.w};
            float vv[8] = {vA.x, vA.y, vA.z, vA.w, vB.x, vB.y, vB.z, vB.w};
            #pragma unroll
            for (int a = 0; a < 4; a++)
                #pragma unroll
                for (int c = 0; c < 8; c++) acc[a][c] += wv[a] * vv[c];
        }
        #pragma unroll
        for (int a = 0; a < 4; a++) {
            int h = hc * 64 + h0 + a;
            float qb = q1b[h], q2v = q2w[h];
            #pragma unroll
            for (int c = 0; c < 8; c++)
                qacc[c] += q2v * gelu_f(acc[a][c] + qb);
        }
    }
    __syncthreads();
    float* sRed = sW;
    *(float4*)&sRed[hg * 132 + y0]     = make_float4(qacc[0], qacc[1], qacc[2], qacc[3]);
    *(float4*)&sRed[hg * 132 + y0 + 4] = make_float4(qacc[4], qacc[5], qacc[6], qacc[7]);
    __syncthreads();
    if (tid < 128) {
        float r = q2b[0];
        #pragma unroll
        for (int g = 0; g < 16; g++) r += sRed[g * 132 + tid];
        out[(b * SS + X) * SS + tid] = r;
    }
}

extern "C" void kernel_launch(void* const* d_in, const int* in_sizes, int n_in,
                              void* d_out, int out_size, void* d_ws, size_t ws_size,
                              hipStream_t stream) {
    const float* x   = (const float*)d_in[0];
    const float* p_w = (const float*)d_in[1];
    const float* p_b = (const float*)d_in[2];
    const float* sw1 = (const float*)d_in[3];
    const float* sw2 = (const float*)d_in[4];
    const float* m1w = (const float*)d_in[5];
    const float* m1b = (const float*)d_in[6];
    const float* m2w = (const float*)d_in[7];
    const float* m2b = (const float*)d_in[8];
    const float* wwp = (const float*)d_in[9];
    const float* wbp = (const float*)d_in[10];
    const float* q1w = (const float*)d_in[11];
    const float* q1b = (const float*)d_in[12];
    const float* q2w = (const float*)d_in[13];
    const float* q2b = (const float*)d_in[14];

    float* ws = (float*)d_ws;
    float*  X0   = ws;                                   // 19,640,320 f
    float*  X1   = X0 + (size_t)BB * CH * CS;            // 19,640,320 f (WS aliases base)
    float*  WS   = X1;                                   // 4,194,304 f (dead before X1 use)
    float*  Tf   = X1 + (size_t)BB * CH * CS;            // 4,489,216 f (T / Hh)
    float2* F    = (float2*)(Tf + (size_t)NROW * 32);    // 524,288 f2 (F / G2)
    float2* G    = F + (size_t)524288;
    float2* Wy   = G + (size_t)524288;
    float2* Wx   = Wy + 2192;
    float2* WyT  = Wx + 4384;
    float*  wcomb = (float*)(WyT + 2192);                // 32768 f
    float*  WTy  = wcomb + 32768;                        // 4608 f

    k_init<<<181, 256, 0, stream>>>(Wy, Wx, WyT, wcomb, WTy, m2w, wwp);
    k_proj<<<(BB * CH * CS) / 256, 256, 0, stream>>>(x, p_w, p_b, X0);
    for (int layer = 0; layer < NL; layer++) {
        k_wtrans<<<16384, 256, 0, stream>>>(sw1, sw2, layer, WS);
        k_dfty3<<<548, 256, 0, stream>>>(X0, Wy, Tf);
        k_dftx2<<<1024, 512, 0, stream>>>(Tf, Wx, F);
        k_specmul2<<<dim3(32, 8), 256, 0, stream>>>(F, (const float2*)WS, G);
        k_mlp1m<<<dim3(16, BB), 128, 0, stream>>>((const float*)G, m1w, layer, (float*)F);
        k_invx2<<<1024, 256, 0, stream>>>(F, Wx, (float2*)Tf);
        k_invy4<<<dim3(HH, BB), 256, 0, stream>>>(Tf, WTy, m1b, layer, X1);
        k_tail3<<<dim3((CS + 127) / 128, BB), 256, 0, stream>>>(X0, X1, wcomb, m2b, wbp, layer);
    }
    k_final5<<<dim3(SS, BB), 256, 0, stream>>>(X0, q1w, q1b, q2w, q2b, (float*)d_out);
}

// Round 8
// 1354.691 us; speedup vs baseline: 1.2677x; 1.0158x over previous
//
#include <hip/hip_runtime.h>
#include <math.h>

#define BB 16
#define CH 64
#define SS 128
#define HH 137
#define XS 140            // padded x-stride (16B-aligned float4)
#define CS (137 * 140)    // per-channel stride = 19180
#define MM 16
#define KK 32
#define NL 4
#define NROW 140288       // BB*CH*HH rows of (bo,x)

__device__ __forceinline__ float gelu_f(float x) {
    return 0.5f * x * (1.0f + erff(x * 0.70710678118654752440f));
}

// ---- init: twiddles + fused tail weights + WTy (32x144 inv-y GEMM weights) ----
__global__ void k_init(float2* __restrict__ Wy, float2* __restrict__ Wx,
                       float* __restrict__ wcomb, float* __restrict__ WTy,
                       const float* __restrict__ m2w, const float* __restrict__ wwp) {
    int t = blockIdx.x * 256 + threadIdx.x;
    const double PI2 = 6.283185307179586476925286766559;
    if (t < 2192) {                       // Wy[y*16+ky]
        int y = t >> 4, k = t & 15;
        int m = (y * k) % HH;
        double ang = -PI2 * (double)m / (double)HH;
        Wy[t] = make_float2((float)cos(ang), (float)sin(ang));
    } else if (t < 6576) {                // Wx[x*32+ki]
        int u = t - 2192;
        int x = u >> 5, ki = u & 31;
        int K = (ki < 16) ? ki : (105 + ki);
        int m = (x * K) % HH;
        double ang = -PI2 * (double)m / (double)HH;
        Wx[u] = make_float2((float)cos(ang), (float)sin(ang));
    } else if (t < 39344) {               // wcomb[layer][i][0..63]=w2^T, [64..127]=ww^T
        int u = t - 6576;
        int layer = u >> 13;
        int r = u & 8191;
        int i = r >> 7, c = r & 127;
        float v;
        if (c < 64) v = m2w[layer * 4096 + c * 64 + i];
        else        v = wwp[layer * 4096 + (c - 64) * 64 + i];
        wcomb[u] = v;
    } else if (t < 43952) {               // WTy[f][y]: f=2ky(+1) -> cos/sin, stride 144, pad 0
        int u = t - 39344;
        int f = u / 144, y = u - f * 144;
        float v = 0.f;
        if (y < HH) {
            int ky = f >> 1;
            int m = (y * ky) % HH;
            double ang = -PI2 * (double)m / (double)HH;
            v = (f & 1) ? (float)sin(ang) : (float)cos(ang);
        }
        WTy[u] = v;
    }
}

// ---- per-layer spectral-weight transpose: WS[kx][ky][i][o] (float2 re/im) ----
__global__ void k_wtrans(const float* __restrict__ sw1, const float* __restrict__ sw2,
                         int layer, float* __restrict__ WS) {
    int d = blockIdx.x * 256 + threadIdx.x;
    int reim = d & 1;
    int o  = (d >> 1) & 63;
    int i  = (d >> 7) & 63;
    int ky = (d >> 13) & 15;
    int kx = (d >> 17) & 31;
    const float* src = (kx < 16) ? sw1 : sw2;
    int kk = kx & 15;
    WS[d] = src[layer * 2097152 + reim * 1048576 + i * 16384 + o * 256 + kk * 16 + ky];
}

// ---- fold mlp1 into spectral weights: WC[mode][i][p] = sc * sum_o WS[mode][i][o]*M[p][o] ----
__global__ void __launch_bounds__(256) k_wmix(const float2* __restrict__ WS,
                                              const float* __restrict__ m1w, int layer,
                                              float2* __restrict__ WC) {
    __shared__ float sWr[64 * 68];   // [o][i] 17.4KB
    __shared__ float sWi[64 * 68];   // 17.4KB
    __shared__ float sM[64 * 68];    // [o][p] 17.4KB
    int tid = threadIdx.x;
    int kx = blockIdx.x, ky = blockIdx.y;
    int mode = kx * 16 + ky;
    const float4* wsrc = (const float4*)(WS + (size_t)mode * 4096);
    for (int idx = tid; idx < 2048; idx += 256) {
        int i = idx >> 5, op = (idx & 31) * 2;
        float4 v = wsrc[idx];
        sWr[op * 68 + i] = v.x;
        sWi[op * 68 + i] = v.y;
        sWr[(op + 1) * 68 + i] = v.z;
        sWi[(op + 1) * 68 + i] = v.w;
    }
    for (int idx = tid; idx < 4096; idx += 256) {
        int p = idx >> 6, o = idx & 63;
        sM[o * 68 + p] = m1w[layer * 4096 + p * 64 + o];
    }
    __syncthreads();
    int ig = tid & 15, pg = tid >> 4;
    int i0 = ig * 4, p0 = pg * 4;
    float ar[4][4], ai[4][4];
    #pragma unroll
    for (int a = 0; a < 4; a++)
        #pragma unroll
        for (int c = 0; c < 4; c++) { ar[a][c] = 0.f; ai[a][c] = 0.f; }
    for (int o = 0; o < 64; o++) {
        float4 wr = *(const float4*)&sWr[o * 68 + i0];
        float4 wi = *(const float4*)&sWi[o * 68 + i0];
        float4 m  = *(const float4*)&sM[o * 68 + p0];
        float rr[4] = {wr.x, wr.y, wr.z, wr.w};
        float ii[4] = {wi.x, wi.y, wi.z, wi.w};
        float mm[4] = {m.x, m.y, m.z, m.w};
        #pragma unroll
        for (int a = 0; a < 4; a++)
            #pragma unroll
            for (int c = 0; c < 4; c++) {
                ar[a][c] += rr[a] * mm[c];
                ai[a][c] += ii[a] * mm[c];
            }
    }
    float sc = (ky == 0 ? 1.0f : 2.0f) / 18769.0f;
    float* out = (float*)(WC + (size_t)mode * 4096);
    #pragma unroll
    for (int a = 0; a < 4; a++) {
        size_t base = (size_t)((i0 + a) * 64 + p0) * 2;
        *(float4*)&out[base]     = make_float4(ar[a][0] * sc, ai[a][0] * sc,
                                               ar[a][1] * sc, ai[a][1] * sc);
        *(float4*)&out[base + 4] = make_float4(ar[a][2] * sc, ai[a][2] * sc,
                                               ar[a][3] * sc, ai[a][3] * sc);
    }
}

// ---- projection into padded X0 ----
__global__ void k_proj(const float* __restrict__ x, const float* __restrict__ pw,
                       const float* __restrict__ pb, float* __restrict__ X0) {
    int t = blockIdx.x * 256 + threadIdx.x;
    int b = t / (CH * CS);
    int r = t - b * (CH * CS);
    int d = r / CS;
    int s = r - d * CS;
    int X = s / XS, Y = s - X * XS;
    float v = 0.f;
    if (X < SS && Y < SS) {
        v = pb[d];
        #pragma unroll
        for (int c = 0; c < 5; c++)
            v += x[((b * 5 + c) * SS + X) * SS + Y] * pw[c * CH + d];
        v += ((float)X * (1.0f / 127.0f)) * pw[5 * CH + d];
        v += ((float)Y * (1.0f / 127.0f)) * pw[6 * CH + d];
    }
    X0[t] = v;
}

// ---- forward DFT along y: coalesced float4 staging + scatter LDS transpose ----
__global__ void __launch_bounds__(256) k_dfty3(const float* __restrict__ X0,
                                               const float2* __restrict__ Wy,
                                               float* __restrict__ Tf) {
    __shared__ float sXT[32 * 260];
    __shared__ float sWy[HH * 32];
    int tid = threadIdx.x;
    int r0b = blockIdx.x * 256;
    int bi0 = r0b / 137;
    int xx0 = r0b - bi0 * 137;
    for (int idx = tid; idx < HH * MM; idx += 256) {
        float2 w = Wy[idx];
        sWy[idx * 2] = w.x;
        sWy[idx * 2 + 1] = w.y;
    }
    int rowg = tid >> 2, kg = tid & 3;
    int r0 = rowg * 4, k0 = kg * 8;
    float acc[4][8];
    #pragma unroll
    for (int a = 0; a < 4; a++)
        #pragma unroll
        for (int c = 0; c < 8; c++) acc[a][c] = 0.f;
    for (int yc = 0; yc < 5; yc++) {
        int y0c = yc * 32;
        int ylen = (y0c + 32 <= HH) ? 32 : (HH - y0c);
        __syncthreads();
        for (int k = 0; k < 8; k++) {
            int idx = k * 256 + tid;
            int r = idx >> 3, q = idx & 7;
            int xx = xx0 + r, bi = bi0;
            if (xx >= 137) { xx -= 137; bi++; }
            if (xx >= 137) { xx -= 137; bi++; }
            int y = y0c + 4 * q;
            size_t off = (size_t)bi * CS + xx * XS + y;
            float4 v;
            if (y + 4 <= HH) {
                v = *(const float4*)&X0[off];
            } else {
                v.x = (y     < HH) ? X0[off]     : 0.f;
                v.y = (y + 1 < HH) ? X0[off + 1] : 0.f;
                v.z = (y + 2 < HH) ? X0[off + 2] : 0.f;
                v.w = (y + 3 < HH) ? X0[off + 3] : 0.f;
            }
            int yy = 4 * q;
            sXT[(yy    ) * 260 + r] = v.x;
            sXT[(yy + 1) * 260 + r] = v.y;
            sXT[(yy + 2) * 260 + r] = v.z;
            sXT[(yy + 3) * 260 + r] = v.w;
        }
        __syncthreads();
        for (int yy = 0; yy < ylen; yy++) {
            int y = y0c + yy;
            float4 wA = *(const float4*)&sWy[y * 32 + k0];
            float4 wB = *(const float4*)&sWy[y * 32 + k0 + 4];
            float4 v  = *(const float4*)&sXT[yy * 260 + r0];
            float wv[8] = {wA.x, wA.y, wA.z, wA.w, wB.x, wB.y, wB.z, wB.w};
            float vv[4] = {v.x, v.y, v.z, v.w};
            #pragma unroll
            for (int a = 0; a < 4; a++)
                #pragma unroll
                for (int c = 0; c < 8; c++) acc[a][c] += vv[a] * wv[c];
        }
    }
    #pragma unroll
    for (int a = 0; a < 4; a++) {
        size_t rb = (size_t)(r0b + r0 + a) * 32 + k0;
        *(float4*)&Tf[rb]     = make_float4(acc[a][0], acc[a][1], acc[a][2], acc[a][3]);
        *(float4*)&Tf[rb + 4] = make_float4(acc[a][4], acc[a][5], acc[a][6], acc[a][7]);
    }
}

// ---- forward DFT along x: LDS-staged per (b,i) ----
__global__ void __launch_bounds__(512) k_dftx2(const float* __restrict__ Tf,
                                               const float2* __restrict__ Wx,
                                               float2* __restrict__ F) {
    __shared__ float sT[HH * 32];
    __shared__ float2 sWx[HH * 32];
    int tid = threadIdx.x;
    int bi = blockIdx.x;
    const float4* tg = (const float4*)(Tf + (size_t)bi * (HH * 32));
    for (int idx = tid; idx < HH * 8; idx += 512) ((float4*)sT)[idx] = tg[idx];
    const float4* wg = (const float4*)Wx;
    for (int idx = tid; idx < HH * 16; idx += 512) ((float4*)sWx)[idx] = wg[idx];
    __syncthreads();
    int ky = tid & 15, kx = tid >> 4;
    float fr = 0.f, fi = 0.f;
    const float2* sT2 = (const float2*)sT;
    #pragma unroll 4
    for (int x = 0; x < HH; x++) {
        float2 t = sT2[x * 16 + ky];
        float2 w = sWx[x * 32 + kx];
        fr += t.x * w.x - t.y * w.y;
        fi += t.x * w.y + t.y * w.x;
    }
    F[(size_t)bi * 512 + tid] = make_float2(fr, fi);
}

// ---- spectral multiply with combined (mlp1-folded, scaled) weights ----
__global__ void __launch_bounds__(256) k_specmul2(const float2* __restrict__ F,
                                                  const float2* __restrict__ WC,
                                                  float2* __restrict__ G) {
    int tid = threadIdx.x;
    int o = tid & 63;
    int kyq = __builtin_amdgcn_readfirstlane(tid >> 6);
    int kx = blockIdx.x;
    int b = blockIdx.y;
    float gr[4], gi[4];
    #pragma unroll
    for (int j = 0; j < 4; j++) { gr[j] = 0.f; gi[j] = 0.f; }
    for (int i = 0; i < CH; i++) {
        const float2* Fb = F + ((size_t)(b * CH + i) * KK + kx) * MM + kyq * 4;
        const float2* Wb = WC + ((size_t)(kx * MM + kyq * 4) * CH + i) * CH + o;
        #pragma unroll
        for (int j = 0; j < 4; j++) {
            float2 f = Fb[j];
            float2 w = Wb[(size_t)j * CH * CH];
            gr[j] += f.x * w.x - f.y * w.y;
            gi[j] += f.x * w.y + f.y * w.x;
        }
    }
    float* Gf = (float*)G;
    size_t base = (((size_t)(b * CH + o) * KK + kx) * MM + kyq * 4) * 2;
    *(float4*)&Gf[base]     = make_float4(gr[0], gi[0], gr[1], gi[1]);
    *(float4*)&Gf[base + 4] = make_float4(gr[2], gi[2], gr[3], gi[3]);
}

// ---- fused inverse x-DFT + inverse y-DFT + mlp1 bias + gelu: X1[bo][x][y] ----
// block per (b,o); phase A: inv-x into sH[k=2ky(+1)][x]; phase B: K=32 micro-GEMM over (x,y)
__global__ void __launch_bounds__(256) k_invxy(const float2* __restrict__ G,
                                               const float2* __restrict__ Wx,
                                               const float* __restrict__ WTy,
                                               const float* __restrict__ m1b, int layer,
                                               float* __restrict__ X1) {
    __shared__ float2 sG[512];         // 4KB
    __shared__ float sH[32 * 140];     // 17.9KB [k][x]
    __shared__ float sWy[32 * 144];    // 18.4KB [k][y]
    int tid = threadIdx.x;
    int bo = blockIdx.x;
    int o = bo & 63;
    ((float4*)sG)[tid] = ((const float4*)(G + (size_t)bo * 512))[tid];
    for (int idx = tid; idx < 1152; idx += 256)
        ((float4*)sWy)[idx] = ((const float4*)WTy)[idx];
    __syncthreads();
    // phase A: inverse x-DFT (scale already folded into WC)
    for (int it = 0; it < 9; it++) {
        int item = it * 256 + tid;
        if (item < HH * 16) {
            int x = item >> 4, ky = item & 15;
            float hr = 0.f, hi = 0.f;
            #pragma unroll 8
            for (int kx = 0; kx < KK; kx++) {
                float2 g = sG[kx * 16 + ky];
                float2 w = Wx[x * KK + kx];
                hr += g.x * w.x + g.y * w.y;
                hi += g.y * w.x - g.x * w.y;
            }
            sH[(2 * ky) * 140 + x] = hr;
            sH[(2 * ky + 1) * 140 + x] = hi;
        }
    }
    __syncthreads();
    float b1v = m1b[layer * CH + o];
    size_t rbase = (size_t)bo * CS;
    // phase B: tiles of 4x * 8y over (35 x-tiles, 18 y-tiles) = 630 tiles
    for (int pass = 0; pass < 3; pass++) {
        int tt = pass * 256 + tid;
        if (tt >= 630) break;
        int xg = tt / 18, yg = tt - xg * 18;
        int x0 = xg * 4, y0 = yg * 8;
        float acc[4][8];
        #pragma unroll
        for (int a = 0; a < 4; a++)
            #pragma unroll
            for (int c = 0; c < 8; c++) acc[a][c] = 0.f;
        #pragma unroll 8
        for (int k = 0; k < 32; k++) {
            float4 a4 = *(const float4*)&sH[k * 140 + x0];
            float4 wA = *(const float4*)&sWy[k * 144 + y0];
            float4 wB = *(const float4*)&sWy[k * 144 + y0 + 4];
            float aa[4] = {a4.x, a4.y, a4.z, a4.w};
            float wv[8] = {wA.x, wA.y, wA.z, wA.w, wB.x, wB.y, wB.z, wB.w};
            #pragma unroll
            for (int a = 0; a < 4; a++)
                #pragma unroll
                for (int c = 0; c < 8; c++) acc[a][c] += aa[a] * wv[c];
        }
        #pragma unroll
        for (int a = 0; a < 4; a++) {
            int x = x0 + a;
            if (x >= HH) continue;
            float g[8];
            #pragma unroll
            for (int c = 0; c < 8; c++) g[c] = gelu_f(acc[a][c] + b1v);
            size_t base = rbase + (size_t)x * XS + y0;
            if (y0 + 8 <= HH) {
                *(float4*)&X1[base]     = make_float4(g[0], g[1], g[2], g[3]);
                *(float4*)&X1[base + 4] = make_float4(g[4], g[5], g[6], g[7]);
            } else {
                #pragma unroll
                for (int c = 0; c < 8; c++)
                    if (y0 + c < HH) X1[base + c] = g[c];
            }
        }
    }
}

// ---- tail: X0 = gelu(w2.X1 + ww.X0 + b2 + wb), 2-pass LDS micro-GEMM, in-place ----
__global__ void __launch_bounds__(256) k_tail3(float* __restrict__ X0,
    const float* __restrict__ X1, const float* __restrict__ wcomb,
    const float* __restrict__ b2, const float* __restrict__ wb, int layer) {
    __shared__ float sV[CH * 132];   // 33.8KB
    __shared__ float sW[CH * 68];    // 17.4KB
    int tid = threadIdx.x;
    int b = blockIdx.y;
    int s0 = blockIdx.x * 128;
    int og = tid & 15, pg = tid >> 4;
    int o0 = og * 4, p0 = pg * 8;
    float acc[4][8];
    #pragma unroll
    for (int a = 0; a < 4; a++)
        #pragma unroll
        for (int c = 0; c < 8; c++) acc[a][c] = 0.f;
    const float* wl = wcomb + layer * 8192;

    #pragma unroll
    for (int pass = 0; pass < 2; pass++) {
        const float* src = pass ? X0 : X1;
        for (int idx = tid; idx < 2048; idx += 256) {
            int i = idx >> 5, p4 = (idx & 31) * 4;
            float4 v = make_float4(0.f, 0.f, 0.f, 0.f);
            int s = s0 + p4;
            if (s + 4 <= CS) v = *(const float4*)&src[(size_t)(b * CH + i) * CS + s];
            *(float4*)&sV[i * 132 + p4] = v;
        }
        for (int idx = tid; idx < 4096; idx += 256) {
            int i = idx >> 6, o = idx & 63;
            sW[i * 68 + o] = wl[i * 128 + (pass ? 64 + o : o)];
        }
        __syncthreads();
        for (int i = 0; i < CH; i++) {
            float4 w  = *(const float4*)&sW[i * 68 + o0];
            float4 vA = *(const float4*)&sV[i * 132 + p0];
            float4 vB = *(const float4*)&sV[i * 132 + p0 + 4];
            float wv[4] = {w.x, w.y, w.z, w.w};
            float vv[8] = {vA.x, vA.y, vA.z, vA.w, vB.x, vB.y, vB.z, vB.w};
            #pragma unroll
            for (int a = 0; a < 4; a++)
                #pragma unroll
                for (int c = 0; c < 8; c++) acc[a][c] += wv[a] * vv[c];
        }
        __syncthreads();
    }
    #pragma unroll
    for (int a = 0; a < 4; a++) {
        float bia = b2[layer * CH + o0 + a] + wb[layer * CH + o0 + a];
        float g[8];
        #pragma unroll
        for (int c = 0; c < 8; c++) g[c] = gelu_f(acc[a][c] + bia);
        size_t rowb = (size_t)(b * CH + o0 + a) * CS + s0 + p0;
        if (s0 + p0 + 4 <= CS)
            *(float4*)&X0[rowb] = make_float4(g[0], g[1], g[2], g[3]);
        if (s0 + p0 + 8 <= CS)
            *(float4*)&X0[rowb + 4] = make_float4(g[4], g[5], g[6], g[7]);
    }
}

// ---- final head: LDS micro-GEMM ----
__global__ void __launch_bounds__(256) k_final5(const float* __restrict__ X0,
    const float* __restrict__ q1w, const float* __restrict__ q1b,
    const float* __restrict__ q2w, const float* __restrict__ q2b,
    float* __restrict__ out) {
    __shared__ float sV[CH * 132];
    __shared__ float sW[CH * 68];
    int tid = threadIdx.x;
    int b = blockIdx.y;
    int X = blockIdx.x;
    for (int k = 0; k < 8; k++) {
        int idx = k * 256 + tid;
        int i = idx >> 5, yq = idx & 31;
        *(float4*)&sV[i * 132 + yq * 4] =
            *(const float4*)&X0[(size_t)(b * CH + i) * CS + X * XS + yq * 4];
    }
    int hg = tid & 15, yg = tid >> 4;
    int h0 = hg * 4, y0 = yg * 8;
    float qacc[8];
    #pragma unroll
    for (int c = 0; c < 8; c++) qacc[c] = 0.f;
    for (int hc = 0; hc < 4; hc++) {
        __syncthreads();
        for (int idx = tid; idx < 4096; idx += 256) {
            int h = idx >> 6, i = idx & 63;
            sW[i * 68 + h] = q1w[(hc * 64 + h) * 64 + i];
        }
        __syncthreads();
        float acc[4][8];
        #pragma unroll
        for (int a = 0; a < 4; a++)
            #pragma unroll
            for (int c = 0; c < 8; c++) acc[a][c] = 0.f;
        for (int i = 0; i < CH; i++) {
            float4 w  = *(const float4*)&sW[i * 68 + h0];
            float4 vA = *(const float4*)&sV[i * 132 + y0];
            float4 vB = *(const float4*)&sV[i * 132 + y0 + 4];
            float wv[4] = {w.x, w.y, w.z, w.w};
            float vv[8] = {vA.x, vA.y, vA.z, vA.w, vB.x, vB.y, vB.z, vB.w};
            #pragma unroll
            for (int a = 0; a < 4; a++)
                #pragma unroll
                for (int c = 0; c < 8; c++) acc[a][c] += wv[a] * vv[c];
        }
        #pragma unroll
        for (int a = 0; a < 4; a++) {
            int h = hc * 64 + h0 + a;
            float qb = q1b[h], q2v = q2w[h];
            #pragma unroll
            for (int c = 0; c < 8; c++)
                qacc[c] += q2v * gelu_f(acc[a][c] + qb);
        }
    }
    __syncthreads();
    float* sRed = sW;
    *(float4*)&sRed[hg * 132 + y0]     = make_float4(qacc[0], qacc[1], qacc[2], qacc[3]);
    *(float4*)&sRed[hg * 132 + y0 + 4] = make_float4(qacc[4], qacc[5], qacc[6], qacc[7]);
    __syncthreads();
    if (tid < 128) {
        float r = q2b[0];
        #pragma unroll
        for (int g = 0; g < 16; g++) r += sRed[g * 132 + tid];
        out[(b * SS + X) * SS + tid] = r;
    }
}

extern "C" void kernel_launch(void* const* d_in, const int* in_sizes, int n_in,
                              void* d_out, int out_size, void* d_ws, size_t ws_size,
                              hipStream_t stream) {
    const float* x   = (const float*)d_in[0];
    const float* p_w = (const float*)d_in[1];
    const float* p_b = (const float*)d_in[2];
    const float* sw1 = (const float*)d_in[3];
    const float* sw2 = (const float*)d_in[4];
    const float* m1w = (const float*)d_in[5];
    const float* m1b = (const float*)d_in[6];
    const float* m2w = (const float*)d_in[7];
    const float* m2b = (const float*)d_in[8];
    const float* wwp = (const float*)d_in[9];
    const float* wbp = (const float*)d_in[10];
    const float* q1w = (const float*)d_in[11];
    const float* q1b = (const float*)d_in[12];
    const float* q2w = (const float*)d_in[13];
    const float* q2b = (const float*)d_in[14];

    float* ws = (float*)d_ws;
    float*  X0   = ws;                                   // 19,640,320 f
    float*  X1   = X0 + (size_t)BB * CH * CS;            // 19,640,320 f
    float*  WS   = X1;                                   // 16.8MB, dead before X1 written
    float*  WC   = X1 + (size_t)4194304;                 // 16.8MB, dead before X1 written
    float*  Tf   = X1 + (size_t)BB * CH * CS;            // 4,489,216 f
    float2* F    = (float2*)(Tf + (size_t)NROW * 32);    // 524,288 f2
    float2* G    = F + (size_t)524288;
    float2* Wy   = G + (size_t)524288;
    float2* Wx   = Wy + 2192;
    float*  wcomb = (float*)(Wx + 4384);                 // 32768 f
    float*  WTy  = wcomb + 32768;                        // 4608 f

    k_init<<<172, 256, 0, stream>>>(Wy, Wx, wcomb, WTy, m2w, wwp);
    k_proj<<<(BB * CH * CS) / 256, 256, 0, stream>>>(x, p_w, p_b, X0);
    for (int layer = 0; layer < NL; layer++) {
        k_wtrans<<<16384, 256, 0, stream>>>(sw1, sw2, layer, WS);
        k_wmix<<<dim3(32, 16), 256, 0, stream>>>((const float2*)WS, m1w, layer, (float2*)WC);
        k_dfty3<<<548, 256, 0, stream>>>(X0, Wy, Tf);
        k_dftx2<<<1024, 512, 0, stream>>>(Tf, Wx, F);
        k_specmul2<<<dim3(32, BB), 256, 0, stream>>>(F, (const float2*)WC, G);
        k_invxy<<<1024, 256, 0, stream>>>(G, Wx, WTy, m1b, layer, X1);
        k_tail3<<<dim3((CS + 127) / 128, BB), 256, 0, stream>>>(X0, X1, wcomb, m2b, wbp, layer);
    }
    k_final5<<<dim3(SS, BB), 256, 0, stream>>>(X0, q1w, q1b, q2w, q2b, (float*)d_out);
}